// Round 1
// baseline (3162.873 us; speedup 1.0000x reference)
//
#include <hip/hip_runtime.h>
#include <hip/hip_bf16.h>
#include <stdint.h>

// ---------------- problem constants ----------------
#define BB   4
#define SS   1024
#define DD   1024
#define HH   16
#define LL   4
#define VV   32000
#define DHH  64
#define DFFN 4096
#define BSZ  4096   // B*S

typedef __hip_bfloat16 bf16_t;
typedef _Float16 f16_t;
typedef __attribute__((ext_vector_type(8))) _Float16 f16x8;
typedef __attribute__((ext_vector_type(4))) float    f4v;

typedef __attribute__((address_space(1))) const void gvoid_t;
typedef __attribute__((address_space(3))) void       svoid_t;

static_assert(sizeof(f16_t) == 2, "f16 size");

// async global->LDS, 16B per lane; LDS dest must be wave-uniform-base + lane*16
__device__ __forceinline__ void gl2lds16(const f16_t* g, f16_t* l) {
  __builtin_amdgcn_global_load_lds(
      reinterpret_cast<gvoid_t*>(reinterpret_cast<uintptr_t>(g)),
      reinterpret_cast<svoid_t*>(static_cast<uint32_t>(reinterpret_cast<uintptr_t>(l))),
      16, 0, 0);
}

// read a float from src interpreted per mode: 0=f32, 1=bf16, 2=f16
__device__ __forceinline__ float readf(const void* src, long i, int m) {
  if (m == 1) return __bfloat162float(((const bf16_t*)src)[i]);
  if (m == 2) return (float)((const f16_t*)src)[i];
  return ((const float*)src)[i];
}

// ---------------- dtype detection ----------------
__global__ void detect_k(const unsigned int* __restrict__ src, int* __restrict__ flag) {
  __shared__ int cnt;
  int tid = threadIdx.x;
  if (tid == 0) cnt = 0;
  __syncthreads();
  int c = 0;
  for (int i = tid; i < 1024; i += 256) {
    unsigned int w = src[i] & 0xffffu;
    unsigned int e = (w >> 7) & 0xffu;
    c += (e >= 96 && e <= 150) ? 1 : 0;
  }
  atomicAdd(&cnt, c);
  __syncthreads();
  if (tid == 0) *flag = (cnt >= 512) ? 1 : 0;
}

// ---------------- converts ----------------
__global__ __launch_bounds__(256) void conv_f16_k(const void* __restrict__ src, f16_t* __restrict__ dst,
                                                  long n, const int* __restrict__ flag, int mode) {
  int m = (mode < 0) ? *flag : mode;
  long i = (long)blockIdx.x * blockDim.x + threadIdx.x;
  long stride = (long)gridDim.x * blockDim.x;
  for (; i < n; i += stride) dst[i] = (f16_t)readf(src, i, m);
}

__global__ __launch_bounds__(256) void conv_f32_k(const void* __restrict__ src, float* __restrict__ dst,
                                                  long n, const int* __restrict__ flag) {
  int m = *flag;
  long i = (long)blockIdx.x * blockDim.x + threadIdx.x;
  long stride = (long)gridDim.x * blockDim.x;
  for (; i < n; i += stride) dst[i] = readf(src, i, m);
}

// batched transpose+convert: src batch z is (R x C) row-major (stride R*C),
// dst batch z base = (z/zper)*dstL + (z%zper)*dstH, batch is (C x R) f16.
__global__ __launch_bounds__(256) void transpose_k(const void* __restrict__ src, f16_t* __restrict__ dst,
                                                   int R, int C, const int* __restrict__ flag, int mode,
                                                   long dstL, int zper, long dstH) {
  int m = (mode < 0) ? *flag : mode;
  __shared__ float t[32][33];
  int tx = threadIdx.x, ty = threadIdx.y;
  long sbase = (long)blockIdx.z * R * C;
  long dbase = (long)(blockIdx.z / zper) * dstL + (long)(blockIdx.z % zper) * dstH;
  int c = blockIdx.x * 32 + tx;
#pragma unroll
  for (int i = 0; i < 4; ++i) {
    int r = blockIdx.y * 32 + ty + i * 8;
    t[ty + i * 8][tx] = (r < R && c < C) ? readf(src, sbase + (long)r * C + c, m) : 0.f;
  }
  __syncthreads();
#pragma unroll
  for (int i = 0; i < 4; ++i) {
    int oc = blockIdx.x * 32 + ty + i * 8;  // original col -> output row
    int orw = blockIdx.y * 32 + tx;         // original row -> output col
    if (oc < C && orw < R) dst[dbase + (long)oc * R + orw] = (f16_t)t[tx][ty + i * 8];
  }
}

// ---------------- embedding ----------------
__global__ __launch_bounds__(256) void embed_k(const int* __restrict__ tok, const f16_t* __restrict__ E,
                                               const f16_t* __restrict__ P, float* __restrict__ X) {
  int mrow = blockIdx.x;
  int s = mrow & (SS - 1);
  long eb = (long)tok[mrow] * DD;
  long pb = (long)s * DD;
  int d = threadIdx.x * 4;
  float4 o;
  o.x = (float)E[eb + d + 0] + (float)P[pb + d + 0];
  o.y = (float)E[eb + d + 1] + (float)P[pb + d + 1];
  o.z = (float)E[eb + d + 2] + (float)P[pb + d + 2];
  o.w = (float)E[eb + d + 3] + (float)P[pb + d + 3];
  ((float4*)(X + (long)mrow * DD))[threadIdx.x] = o;
}

// ---------------- layernorm (fp32 in, f16 out) ----------------
__global__ __launch_bounds__(256) void ln_k(const float* __restrict__ X, const float* __restrict__ g,
                                            const float* __restrict__ be, f16_t* __restrict__ out) {
  __shared__ float red1[4], red2[4];
  int row = blockIdx.x, tid = threadIdx.x;
  float4 x = ((const float4*)(X + (long)row * DD))[tid];
  float s = x.x + x.y + x.z + x.w;
#pragma unroll
  for (int o = 32; o; o >>= 1) s += __shfl_down(s, o);
  if ((tid & 63) == 0) red1[tid >> 6] = s;
  __syncthreads();
  float mean = (red1[0] + red1[1] + red1[2] + red1[3]) * (1.f / DD);
  float d0 = x.x - mean, d1 = x.y - mean, d2 = x.z - mean, d3 = x.w - mean;
  float v = d0 * d0 + d1 * d1 + d2 * d2 + d3 * d3;
#pragma unroll
  for (int o = 32; o; o >>= 1) v += __shfl_down(v, o);
  if ((tid & 63) == 0) red2[tid >> 6] = v;
  __syncthreads();
  float rs = rsqrtf((red2[0] + red2[1] + red2[2] + red2[3]) * (1.f / DD) + 1e-5f);
  int d = tid * 4;
  union { ushort4 u4; f16_t h[4]; } o;
  o.h[0] = (f16_t)(d0 * rs * g[d + 0] + be[d + 0]);
  o.h[1] = (f16_t)(d1 * rs * g[d + 1] + be[d + 1]);
  o.h[2] = (f16_t)(d2 * rs * g[d + 2] + be[d + 2]);
  o.h[3] = (f16_t)(d3 * rs * g[d + 3] + be[d + 3]);
  ((ushort4*)(out + (long)row * DD))[tid] = o.u4;
}

// ---------------- softmax over materialized f16 scores, IN-PLACE ----------------
// sc/pr may alias (each thread reads then writes only its own elements of its row).
// z = z0 + zl (global), z = h*BB + b. Mask = causal & qpad & kpad; pad-query row -> uniform 1/S
__global__ __launch_bounds__(256) void softmax_k(const f16_t* __restrict__ sc, f16_t* __restrict__ pr,
                                                 const int* __restrict__ tok, int z0) {
  __shared__ float red1[4], red2[4];
  int s = blockIdx.x, zl = blockIdx.y, tid = threadIdx.x;
  int z = z0 + zl;
  int b = z & (BB - 1);
  const f16_t* srow = sc + ((long)zl * SS + s) * SS;
  f16_t* prow = pr + ((long)zl * SS + s) * SS;
  const int* tb = tok + b * SS;
  if (tb[s] == 0) {  // pad query: reference softmax of all -1e9 -> uniform
    for (int k = tid; k < SS; k += 256) prow[k] = (f16_t)(1.0f / SS);
    return;
  }
  float val[4]; bool vld[4];
  float mx = -3e38f;
#pragma unroll
  for (int i = 0; i < 4; ++i) {
    int k = tid + i * 256;
    bool valid = (k <= s) && (tb[k] != 0);
    float v = valid ? (float)srow[k] * 0.125f : -3e38f;  // scale = 1/sqrt(64)
    val[i] = v; vld[i] = valid;
    mx = fmaxf(mx, v);
  }
#pragma unroll
  for (int o = 32; o; o >>= 1) mx = fmaxf(mx, __shfl_down(mx, o));
  if ((tid & 63) == 0) red1[tid >> 6] = mx;
  __syncthreads();
  mx = fmaxf(fmaxf(red1[0], red1[1]), fmaxf(red1[2], red1[3]));
  float e[4]; float sum = 0.f;
#pragma unroll
  for (int i = 0; i < 4; ++i) { e[i] = vld[i] ? __expf(val[i] - mx) : 0.f; sum += e[i]; }
#pragma unroll
  for (int o = 32; o; o >>= 1) sum += __shfl_down(sum, o);
  if ((tid & 63) == 0) red2[tid >> 6] = sum;
  __syncthreads();
  float inv = 1.0f / (red2[0] + red2[1] + red2[2] + red2[3]);
#pragma unroll
  for (int i = 0; i < 4; ++i) prow[tid + i * 256] = (f16_t)(e[i] * inv);
}

// ---------------- the GEMM: C_z = A_z * B_z^T(storage) ----------------
// A: (M x K) row-major f16, lda. B-storage: (N x K) row-major f16, ldb.
// Tile 128 x BN (BN=128 or 64), BK=32, 256 threads = 4 waves (2x2), mfma_f32_16x16x32_f16.
// EPI: 0 plain f32   1 QKV head-split f16->[t*16+h][b*S+s][e] (+bias, bstr between tensors)
//      2 plain f16   3 f32 +bias +residual   4 f16 +bias +relu   6 flag-dtype out
struct GemmP {
  const f16_t* A; const f16_t* B; void* C;
  int M, N, K, lda, ldb, ldc;
  long sAz, sBz;
  int z0, zdiv, czmode;
  long sCz1, sCz2;
  const float* bias;
  long bstr;               // EPI==1: bias idx = (gc>>10)*bstr + (gc&1023)
  const float* resid;
  const int* flag;
};

template <int EPI, bool SKIPU, int BN>
__global__ __launch_bounds__(256) void gemm_bt(GemmP p) {
  int bx = blockIdx.x, by = blockIdx.y, bz = blockIdx.z;
  if (SKIPU && bx > by) return;  // causal: upper tiles never read
  constexpr int NJ = BN / 32;    // n-subtiles per wave
  __shared__ __align__(16) f16_t la[128 * 32];
  __shared__ __align__(16) f16_t lb[BN * 32];
  int tid = threadIdx.x;
  const f16_t* Ab = p.A + (long)bz * p.sAz;
  const f16_t* Bb = p.B + (long)bz * p.sBz;

  int r0 = tid >> 2;
  int c8 = (tid & 3) << 3;
  long ar0 = (long)by * 128 + r0;
  long ar1 = ar0 + 64;
  int brow0 = bx * BN + r0;      if (brow0 > p.N - 1) brow0 = p.N - 1;
  const f16_t* ag0 = Ab + ar0 * p.lda + c8;
  const f16_t* ag1 = Ab + ar1 * p.lda + c8;
  const f16_t* bg0 = Bb + (long)brow0 * p.ldb + c8;
  const f16_t* bg1 = nullptr;
  if constexpr (BN == 128) {
    int brow1 = bx * BN + 64 + r0; if (brow1 > p.N - 1) brow1 = p.N - 1;
    bg1 = Bb + (long)brow1 * p.ldb + c8;
  }
  f16_t* la0 = la + tid * 8; f16_t* la1 = la + 2048 + tid * 8;
  f16_t* lb0 = lb + tid * 8; f16_t* lb1 = lb + 2048 + tid * 8;

  int w = tid >> 6, l = tid & 63;
  int wm = (w >> 1) << 6, wn = (w & 1) * (BN / 2);
  int lr = l & 15, q = l >> 4;

  f4v acc[4][NJ];
  f4v zero = {0.f, 0.f, 0.f, 0.f};
#pragma unroll
  for (int i = 0; i < 4; ++i)
#pragma unroll
    for (int j = 0; j < NJ; ++j) acc[i][j] = zero;

  int nk = p.K >> 5;
  for (int kt = 0; kt < nk; ++kt) {
    __syncthreads();
    long ko = (long)kt << 5;
    gl2lds16(ag0 + ko, la0);
    gl2lds16(ag1 + ko, la1);
    gl2lds16(bg0 + ko, lb0);
    if constexpr (BN == 128) gl2lds16(bg1 + ko, lb1);
    __syncthreads();
    f16x8 af[4], bfr[NJ];
#pragma unroll
    for (int i = 0; i < 4; ++i) af[i] = *(const f16x8*)(la + (wm + i * 16 + lr) * 32 + q * 8);
#pragma unroll
    for (int j = 0; j < NJ; ++j) bfr[j] = *(const f16x8*)(lb + (wn + j * 16 + lr) * 32 + q * 8);
#pragma unroll
    for (int i = 0; i < 4; ++i)
#pragma unroll
      for (int j = 0; j < NJ; ++j)
        acc[i][j] = __builtin_amdgcn_mfma_f32_16x16x32_f16(af[i], bfr[j], acc[i][j], 0, 0, 0);
  }

  long cz;
  if (p.czmode == 1) { int z = p.z0 + bz; cz = (long)(z / p.zdiv) * p.sCz1 + (long)(z % p.zdiv) * p.sCz2; }
  else cz = (long)bz * p.sCz2;
  int flg = 0;
  if constexpr (EPI == 6) flg = *p.flag;

#pragma unroll
  for (int i = 0; i < 4; ++i) {
    int gr0 = by * 128 + wm + i * 16 + q * 4;
#pragma unroll
    for (int j = 0; j < NJ; ++j) {
      int gc = bx * BN + wn + j * 16 + lr;
      if (gc >= p.N) continue;
      float bv = 0.f;
      if constexpr (EPI == 1) bv = p.bias[(long)(gc >> 10) * p.bstr + (gc & (DD - 1))];
      if constexpr (EPI == 3 || EPI == 4) bv = p.bias[gc];
#pragma unroll
      for (int r = 0; r < 4; ++r) {
        int row = gr0 + r;
        if (row >= p.M) continue;
        float v = acc[i][j][r];
        if constexpr (EPI == 0) {
          ((float*)p.C)[cz + (long)row * p.ldc + gc] = v;
        } else if constexpr (EPI == 1) {
          long ad = ((long)(gc >> 6) * p.M + row) * 64 + (gc & 63);
          ((f16_t*)p.C)[ad] = (f16_t)(v + bv);
        } else if constexpr (EPI == 2) {
          ((f16_t*)p.C)[cz + (long)row * p.ldc + gc] = (f16_t)v;
        } else if constexpr (EPI == 3) {
          long ad = cz + (long)row * p.ldc + gc;
          ((float*)p.C)[ad] = v + bv + p.resid[ad];
        } else if constexpr (EPI == 4) {
          float t = v + bv; t = t > 0.f ? t : 0.f;
          ((f16_t*)p.C)[cz + (long)row * p.ldc + gc] = (f16_t)t;
        } else if constexpr (EPI == 6) {
          long ad = cz + (long)row * p.ldc + gc;
          if (flg) ((bf16_t*)p.C)[ad] = __float2bfloat16(v);
          else     ((float*)p.C)[ad] = v;
        }
      }
    }
  }
}

// ---------------- host ----------------
extern "C" void kernel_launch(void* const* d_in, const int* in_sizes, int n_in,
                              void* d_out, int out_size, void* d_ws, size_t ws_size,
                              hipStream_t stream) {
  (void)in_sizes; (void)n_in; (void)out_size;
  const int*  tok = (const int*)d_in[0];
  const void* E_  = d_in[1];  const void* P_  = d_in[2];
  const void* Wq_ = d_in[3];  const void* bq_ = d_in[4];
  const void* Wk_ = d_in[5];  const void* bk_ = d_in[6];
  const void* Wv_ = d_in[7];  const void* bv_ = d_in[8];
  const void* W0_ = d_in[9];  const void* b0_ = d_in[10];
  const void* g1_ = d_in[11]; const void* be1_ = d_in[12];
  const void* g2_ = d_in[13]; const void* be2_ = d_in[14];
  const void* W1_ = d_in[15]; const void* b1_ = d_in[16];
  const void* W2_ = d_in[17]; const void* b2_ = d_in[18];

  char* wsb = (char*)d_ws;
  size_t off = 0;
  auto alloc = [&](size_t bytes) -> void* {
    off = (off + 255) & ~(size_t)255;
    void* p = wsb + off;
    off += bytes;
    return p;
  };

  int*    flag  = (int*)alloc(4);
  f16_t*  Ef    = (f16_t*)alloc((size_t)VV * DD * 2);
  f16_t*  Pf    = (f16_t*)alloc((size_t)SS * DD * 2);
  f16_t*  Wqkvt = (f16_t*)alloc((size_t)LL * 3 * DD * DD * 2); // [l][t*1024+h*64+e][d]
  f16_t*  W0t   = (f16_t*)alloc((size_t)LL * DD * DD * 2);     // [l][n][d]
  f16_t*  W1t   = (f16_t*)alloc((size_t)LL * DFFN * DD * 2);
  f16_t*  W2t   = (f16_t*)alloc((size_t)LL * DD * DFFN * 2);
  float*  bqkvf = (float*)alloc((size_t)3 * LL * HH * DHH * 4); // [t][l][h][e]
  float*  b0f   = (float*)alloc((size_t)LL * DD * 4);
  float*  b1f   = (float*)alloc((size_t)LL * DFFN * 4);
  float*  b2f   = (float*)alloc((size_t)LL * DD * 4);
  float*  g1f   = (float*)alloc((size_t)LL * DD * 4);
  float*  be1f  = (float*)alloc((size_t)LL * DD * 4);
  float*  g2f   = (float*)alloc((size_t)LL * DD * 4);
  float*  be2f  = (float*)alloc((size_t)LL * DD * 4);
  float*  X     = (float*)alloc((size_t)BSZ * DD * 4);          // fp32 residual stream
  f16_t*  hbuf  = (f16_t*)alloc((size_t)BSZ * DD * 2);
  f16_t*  QKVb  = (f16_t*)alloc((size_t)3 * HH * BB * SS * DHH * 2); // [t*16+h][b*S+s][e]
  f16_t*  Vt    = (f16_t*)alloc((size_t)HH * BB * DHH * SS * 2);     // [h][b][e][s]
  f16_t*  attn  = (f16_t*)alloc((size_t)BSZ * DD * 2);               // [b][s][h*64+e]
  f16_t*  ff    = (f16_t*)alloc((size_t)BSZ * DFFN * 2);

  f16_t* Qb = QKVb;
  f16_t* Kb = QKVb + (size_t)HH * BB * SS * DHH;
  f16_t* Vb = QKVb + (size_t)2 * HH * BB * SS * DHH;

  // attention chunk size (number of (h,b) batches per f16 score buffer; in-place softmax)
  size_t rem = ws_size > off ? ws_size - off : 0;
  int CH = 64;
  while (CH > 1 && ((size_t)CH * SS * SS * 2 + 1024) > rem) CH >>= 1;
  f16_t* scoresB = (f16_t*)alloc((size_t)CH * SS * SS * 2);

  dim3 blk(256);

  // --- dtype detect + ingest ---
  detect_k<<<dim3(1), blk, 0, stream>>>((const unsigned int*)E_, flag);
  conv_f16_k<<<dim3(8192), blk, 0, stream>>>(E_, Ef, (long)VV * DD, flag, -1);
  conv_f16_k<<<dim3(1024), blk, 0, stream>>>(P_, Pf, (long)SS * DD, flag, -1);
  conv_f32_k<<<dim3(16), blk, 0, stream>>>(bq_, bqkvf, (long)LL * HH * DHH, flag);
  conv_f32_k<<<dim3(16), blk, 0, stream>>>(bk_, bqkvf + (size_t)LL * HH * DHH, (long)LL * HH * DHH, flag);
  conv_f32_k<<<dim3(16), blk, 0, stream>>>(bv_, bqkvf + (size_t)2 * LL * HH * DHH, (long)LL * HH * DHH, flag);
  conv_f32_k<<<dim3(16), blk, 0, stream>>>(b0_, b0f, (long)LL * DD, flag);
  conv_f32_k<<<dim3(64), blk, 0, stream>>>(b1_, b1f, (long)LL * DFFN, flag);
  conv_f32_k<<<dim3(16), blk, 0, stream>>>(b2_, b2f, (long)LL * DD, flag);
  conv_f32_k<<<dim3(16), blk, 0, stream>>>(g1_, g1f, (long)LL * DD, flag);
  conv_f32_k<<<dim3(16), blk, 0, stream>>>(be1_, be1f, (long)LL * DD, flag);
  conv_f32_k<<<dim3(16), blk, 0, stream>>>(g2_, g2f, (long)LL * DD, flag);
  conv_f32_k<<<dim3(16), blk, 0, stream>>>(be2_, be2f, (long)LL * DD, flag);

  // weight transposes -> (N,K) f16; QKV interleaved per-layer into Wqkvt
  const long W3 = (long)3 * DD * DD;      // per-layer stride of Wqkvt
  transpose_k<<<dim3(2, 32, LL * HH), dim3(32, 8), 0, stream>>>(Wq_, Wqkvt + 0 * DD * DD, DD, DHH, flag, -1,
                                                                W3, HH, (long)DHH * DD);
  transpose_k<<<dim3(2, 32, LL * HH), dim3(32, 8), 0, stream>>>(Wk_, Wqkvt + 1 * DD * DD, DD, DHH, flag, -1,
                                                                W3, HH, (long)DHH * DD);
  transpose_k<<<dim3(2, 32, LL * HH), dim3(32, 8), 0, stream>>>(Wv_, Wqkvt + 2 * DD * DD, DD, DHH, flag, -1,
                                                                W3, HH, (long)DHH * DD);
  transpose_k<<<dim3(32, 32, LL), dim3(32, 8), 0, stream>>>(W0_, W0t, DD, DD, flag, -1,
                                                            (long)DD * DD, 1, 0);
  transpose_k<<<dim3(128, 32, LL), dim3(32, 8), 0, stream>>>(W1_, W1t, DD, DFFN, flag, -1,
                                                             (long)DD * DFFN, 1, 0);
  transpose_k<<<dim3(32, 128, LL), dim3(32, 8), 0, stream>>>(W2_, W2t, DFFN, DD, flag, -1,
                                                             (long)DFFN * DD, 1, 0);

  // --- embedding ---
  embed_k<<<dim3(BSZ), blk, 0, stream>>>(tok, Ef, Pf, X);

  // --- layers ---
  for (int l = 0; l < LL; ++l) {
    ln_k<<<dim3(BSZ), blk, 0, stream>>>(X, g1f + (long)l * DD, be1f + (long)l * DD, hbuf);

    // fused QKV projection (head-split store into QKVb[t*16+h][b*S+s][e])
    GemmP pq{};
    pq.A = hbuf; pq.lda = DD; pq.M = BSZ; pq.N = 3 * DD; pq.K = DD;
    pq.B = Wqkvt + (long)l * W3; pq.ldb = DD; pq.ldc = 0;
    pq.sAz = 0; pq.sBz = 0;
    pq.z0 = 0; pq.zdiv = 1; pq.czmode = 0; pq.sCz1 = 0; pq.sCz2 = 0;
    pq.C = QKVb; pq.bias = bqkvf + (long)l * HH * DHH; pq.bstr = (long)LL * HH * DHH;
    pq.resid = nullptr; pq.flag = nullptr;
    gemm_bt<1, false, 128><<<dim3(24, 32, 1), blk, 0, stream>>>(pq);

    // V -> Vt [h][b][e][s]
    transpose_k<<<dim3(2, 32, HH * BB), dim3(32, 8), 0, stream>>>((const void*)Vb, Vt, SS, DHH, nullptr, 2,
                                                                  (long)DHH * SS, 1, 0);

    int nch = (HH * BB) / CH;
    for (int c = 0; c < nch; ++c) {
      int z0 = c * CH;
      // scores = Q K^T (lower-triangular tiles only), f16
      GemmP ps{};
      ps.A = Qb + (long)z0 * SS * DHH; ps.sAz = (long)SS * DHH; ps.lda = DHH;
      ps.B = Kb + (long)z0 * SS * DHH; ps.sBz = (long)SS * DHH; ps.ldb = DHH;
      ps.M = SS; ps.N = SS; ps.K = DHH;
      ps.C = scoresB; ps.ldc = SS; ps.czmode = 0; ps.z0 = 0; ps.zdiv = 1;
      ps.sCz1 = 0; ps.sCz2 = (long)SS * SS;
      ps.bias = nullptr; ps.bstr = 0; ps.resid = nullptr; ps.flag = nullptr;
      gemm_bt<2, true, 128><<<dim3(8, 8, CH), blk, 0, stream>>>(ps);

      // softmax in-place over f16 scores
      softmax_k<<<dim3(SS, CH), blk, 0, stream>>>(scoresB, scoresB, tok, z0);

      // attn = P V  -> attn[b][s][h*64+e]   (BN=64 tile: no wasted N)
      GemmP pp{};
      pp.A = scoresB; pp.sAz = (long)SS * SS; pp.lda = SS;
      pp.B = Vt + (long)z0 * DHH * SS; pp.sBz = (long)DHH * SS; pp.ldb = SS;
      pp.M = SS; pp.N = DHH; pp.K = SS;
      pp.C = attn; pp.ldc = DD; pp.czmode = 1; pp.z0 = z0; pp.zdiv = BB;
      pp.sCz1 = DHH; pp.sCz2 = (long)SS * DD;
      pp.bias = nullptr; pp.bstr = 0; pp.resid = nullptr; pp.flag = nullptr;
      gemm_bt<2, false, 64><<<dim3(1, 8, CH), blk, 0, stream>>>(pp);
    }

    // X = attn @ W0^T + b0 + X
    GemmP p0{};
    p0.A = attn; p0.lda = DD; p0.M = BSZ; p0.N = DD; p0.K = DD;
    p0.B = W0t + (long)l * DD * DD; p0.ldb = DD;
    p0.C = X; p0.ldc = DD; p0.czmode = 0; p0.z0 = 0; p0.zdiv = 1;
    p0.sAz = 0; p0.sBz = 0; p0.sCz1 = 0; p0.sCz2 = 0;
    p0.bias = b0f + (long)l * DD; p0.bstr = 0; p0.resid = X; p0.flag = nullptr;
    gemm_bt<3, false, 128><<<dim3(8, 32, 1), blk, 0, stream>>>(p0);

    ln_k<<<dim3(BSZ), blk, 0, stream>>>(X, g2f + (long)l * DD, be2f + (long)l * DD, hbuf);

    // ff = relu(h @ W1^T + b1)
    GemmP p1{};
    p1.A = hbuf; p1.lda = DD; p1.M = BSZ; p1.N = DFFN; p1.K = DD;
    p1.B = W1t + (long)l * DFFN * DD; p1.ldb = DD;
    p1.C = ff; p1.ldc = DFFN; p1.czmode = 0; p1.z0 = 0; p1.zdiv = 1;
    p1.sAz = 0; p1.sBz = 0; p1.sCz1 = 0; p1.sCz2 = 0;
    p1.bias = b1f + (long)l * DFFN; p1.bstr = 0; p1.resid = nullptr; p1.flag = nullptr;
    gemm_bt<4, false, 128><<<dim3(32, 32, 1), blk, 0, stream>>>(p1);

    // X = ff @ W2^T + b2 + X
    GemmP p2{};
    p2.A = ff; p2.lda = DFFN; p2.M = BSZ; p2.N = DD; p2.K = DFFN;
    p2.B = W2t + (long)l * DD * DFFN; p2.ldb = DFFN;
    p2.C = X; p2.ldc = DD; p2.czmode = 0; p2.z0 = 0; p2.zdiv = 1;
    p2.sAz = 0; p2.sBz = 0; p2.sCz1 = 0; p2.sCz2 = 0;
    p2.bias = b2f + (long)l * DD; p2.bstr = 0; p2.resid = X; p2.flag = nullptr;
    gemm_bt<3, false, 128><<<dim3(8, 32, 1), blk, 0, stream>>>(p2);
  }

  // logits = X @ E^T (E storage already (V,D) = (N,K))
  conv_f16_k<<<dim3(4096), blk, 0, stream>>>((const void*)X, hbuf, (long)BSZ * DD, flag, 0);
  GemmP pl{};
  pl.A = hbuf; pl.lda = DD; pl.M = BSZ; pl.N = VV; pl.K = DD;
  pl.B = Ef; pl.ldb = DD;
  pl.C = d_out; pl.ldc = VV; pl.czmode = 0; pl.z0 = 0; pl.zdiv = 1;
  pl.sAz = 0; pl.sBz = 0; pl.sCz1 = 0; pl.sCz2 = 0;
  pl.bias = nullptr; pl.bstr = 0; pl.resid = nullptr; pl.flag = flag;
  gemm_bt<6, false, 128><<<dim3(250, 32, 1), blk, 0, stream>>>(pl);
}

// Round 2
// 2820.031 us; speedup vs baseline: 1.1216x; 1.1216x over previous
//
#include <hip/hip_runtime.h>
#include <hip/hip_bf16.h>
#include <stdint.h>

// ---------------- problem constants ----------------
#define BB   4
#define SS   1024
#define DD   1024
#define HH   16
#define LL   4
#define VV   32000
#define DHH  64
#define DFFN 4096
#define BSZ  4096   // B*S

typedef __hip_bfloat16 bf16_t;
typedef _Float16 f16_t;
typedef __attribute__((ext_vector_type(8))) _Float16 f16x8;
typedef __attribute__((ext_vector_type(4))) float    f4v;

typedef __attribute__((address_space(1))) const void gvoid_t;
typedef __attribute__((address_space(3))) void       svoid_t;

static_assert(sizeof(f16_t) == 2, "f16 size");

// async global->LDS, 16B per lane; LDS dest must be wave-uniform-base + lane*16
__device__ __forceinline__ void gl2lds16(const f16_t* g, f16_t* l) {
  __builtin_amdgcn_global_load_lds(
      reinterpret_cast<gvoid_t*>(reinterpret_cast<uintptr_t>(g)),
      reinterpret_cast<svoid_t*>(static_cast<uint32_t>(reinterpret_cast<uintptr_t>(l))),
      16, 0, 0);
}

// read a float from src interpreted per mode: 0=f32, 1=bf16, 2=f16
__device__ __forceinline__ float readf(const void* src, long i, int m) {
  if (m == 1) return __bfloat162float(((const bf16_t*)src)[i]);
  if (m == 2) return (float)((const f16_t*)src)[i];
  return ((const float*)src)[i];
}

// ---------------- dtype detection ----------------
__global__ void detect_k(const unsigned int* __restrict__ src, int* __restrict__ flag) {
  __shared__ int cnt;
  int tid = threadIdx.x;
  if (tid == 0) cnt = 0;
  __syncthreads();
  int c = 0;
  for (int i = tid; i < 1024; i += 256) {
    unsigned int w = src[i] & 0xffffu;
    unsigned int e = (w >> 7) & 0xffu;
    c += (e >= 96 && e <= 150) ? 1 : 0;
  }
  atomicAdd(&cnt, c);
  __syncthreads();
  if (tid == 0) *flag = (cnt >= 512) ? 1 : 0;
}

// ---------------- converts ----------------
__global__ __launch_bounds__(256) void conv_f16_k(const void* __restrict__ src, f16_t* __restrict__ dst,
                                                  long n, const int* __restrict__ flag, int mode) {
  int m = (mode < 0) ? *flag : mode;
  long i = (long)blockIdx.x * blockDim.x + threadIdx.x;
  long stride = (long)gridDim.x * blockDim.x;
  for (; i < n; i += stride) dst[i] = (f16_t)readf(src, i, m);
}

__global__ __launch_bounds__(256) void conv_f32_k(const void* __restrict__ src, float* __restrict__ dst,
                                                  long n, const int* __restrict__ flag) {
  int m = *flag;
  long i = (long)blockIdx.x * blockDim.x + threadIdx.x;
  long stride = (long)gridDim.x * blockDim.x;
  for (; i < n; i += stride) dst[i] = readf(src, i, m);
}

// batched transpose+convert: src batch z is (R x C) row-major (stride R*C),
// dst batch z base = (z/zper)*dstL + (z%zper)*dstH, batch is (C x R) f16.
__global__ __launch_bounds__(256) void transpose_k(const void* __restrict__ src, f16_t* __restrict__ dst,
                                                   int R, int C, const int* __restrict__ flag, int mode,
                                                   long dstL, int zper, long dstH) {
  int m = (mode < 0) ? *flag : mode;
  __shared__ float t[32][33];
  int tx = threadIdx.x, ty = threadIdx.y;
  long sbase = (long)blockIdx.z * R * C;
  long dbase = (long)(blockIdx.z / zper) * dstL + (long)(blockIdx.z % zper) * dstH;
  int c = blockIdx.x * 32 + tx;
#pragma unroll
  for (int i = 0; i < 4; ++i) {
    int r = blockIdx.y * 32 + ty + i * 8;
    t[ty + i * 8][tx] = (r < R && c < C) ? readf(src, sbase + (long)r * C + c, m) : 0.f;
  }
  __syncthreads();
#pragma unroll
  for (int i = 0; i < 4; ++i) {
    int oc = blockIdx.x * 32 + ty + i * 8;  // original col -> output row
    int orw = blockIdx.y * 32 + tx;         // original row -> output col
    if (oc < C && orw < R) dst[dbase + (long)oc * R + orw] = (f16_t)t[tx][ty + i * 8];
  }
}

// ---------------- embedding ----------------
__global__ __launch_bounds__(256) void embed_k(const int* __restrict__ tok, const f16_t* __restrict__ E,
                                               const f16_t* __restrict__ P, float* __restrict__ X) {
  int mrow = blockIdx.x;
  int s = mrow & (SS - 1);
  long eb = (long)tok[mrow] * DD;
  long pb = (long)s * DD;
  int d = threadIdx.x * 4;
  float4 o;
  o.x = (float)E[eb + d + 0] + (float)P[pb + d + 0];
  o.y = (float)E[eb + d + 1] + (float)P[pb + d + 1];
  o.z = (float)E[eb + d + 2] + (float)P[pb + d + 2];
  o.w = (float)E[eb + d + 3] + (float)P[pb + d + 3];
  ((float4*)(X + (long)mrow * DD))[threadIdx.x] = o;
}

// ---------------- layernorm (fp32 in, f16 out) ----------------
__global__ __launch_bounds__(256) void ln_k(const float* __restrict__ X, const float* __restrict__ g,
                                            const float* __restrict__ be, f16_t* __restrict__ out) {
  __shared__ float red1[4], red2[4];
  int row = blockIdx.x, tid = threadIdx.x;
  float4 x = ((const float4*)(X + (long)row * DD))[tid];
  float s = x.x + x.y + x.z + x.w;
#pragma unroll
  for (int o = 32; o; o >>= 1) s += __shfl_down(s, o);
  if ((tid & 63) == 0) red1[tid >> 6] = s;
  __syncthreads();
  float mean = (red1[0] + red1[1] + red1[2] + red1[3]) * (1.f / DD);
  float d0 = x.x - mean, d1 = x.y - mean, d2 = x.z - mean, d3 = x.w - mean;
  float v = d0 * d0 + d1 * d1 + d2 * d2 + d3 * d3;
#pragma unroll
  for (int o = 32; o; o >>= 1) v += __shfl_down(v, o);
  if ((tid & 63) == 0) red2[tid >> 6] = v;
  __syncthreads();
  float rs = rsqrtf((red2[0] + red2[1] + red2[2] + red2[3]) * (1.f / DD) + 1e-5f);
  int d = tid * 4;
  union { ushort4 u4; f16_t h[4]; } o;
  o.h[0] = (f16_t)(d0 * rs * g[d + 0] + be[d + 0]);
  o.h[1] = (f16_t)(d1 * rs * g[d + 1] + be[d + 1]);
  o.h[2] = (f16_t)(d2 * rs * g[d + 2] + be[d + 2]);
  o.h[3] = (f16_t)(d3 * rs * g[d + 3] + be[d + 3]);
  ((ushort4*)(out + (long)row * DD))[tid] = o.u4;
}

// ---------------- softmax over materialized f16 scores, IN-PLACE ----------------
__global__ __launch_bounds__(256) void softmax_k(const f16_t* __restrict__ sc, f16_t* __restrict__ pr,
                                                 const int* __restrict__ tok, int z0) {
  __shared__ float red1[4], red2[4];
  int s = blockIdx.x, zl = blockIdx.y, tid = threadIdx.x;
  int z = z0 + zl;
  int b = z & (BB - 1);
  const f16_t* srow = sc + ((long)zl * SS + s) * SS;
  f16_t* prow = pr + ((long)zl * SS + s) * SS;
  const int* tb = tok + b * SS;
  if (tb[s] == 0) {  // pad query: reference softmax of all -1e9 -> uniform
    for (int k = tid; k < SS; k += 256) prow[k] = (f16_t)(1.0f / SS);
    return;
  }
  float val[4]; bool vld[4];
  float mx = -3e38f;
#pragma unroll
  for (int i = 0; i < 4; ++i) {
    int k = tid + i * 256;
    bool valid = (k <= s) && (tb[k] != 0);
    float v = valid ? (float)srow[k] * 0.125f : -3e38f;  // scale = 1/sqrt(64)
    val[i] = v; vld[i] = valid;
    mx = fmaxf(mx, v);
  }
#pragma unroll
  for (int o = 32; o; o >>= 1) mx = fmaxf(mx, __shfl_down(mx, o));
  if ((tid & 63) == 0) red1[tid >> 6] = mx;
  __syncthreads();
  mx = fmaxf(fmaxf(red1[0], red1[1]), fmaxf(red1[2], red1[3]));
  float e[4]; float sum = 0.f;
#pragma unroll
  for (int i = 0; i < 4; ++i) { e[i] = vld[i] ? __expf(val[i] - mx) : 0.f; sum += e[i]; }
#pragma unroll
  for (int o = 32; o; o >>= 1) sum += __shfl_down(sum, o);
  if ((tid & 63) == 0) red2[tid >> 6] = sum;
  __syncthreads();
  float inv = 1.0f / (red2[0] + red2[1] + red2[2] + red2[3]);
#pragma unroll
  for (int i = 0; i < 4; ++i) prow[tid + i * 256] = (f16_t)(e[i] * inv);
}

// ---------------- legacy GEMM (128 x BN tile): C_z = A_z * B_z^T(storage) ----------------
struct GemmP {
  const f16_t* A; const f16_t* B; void* C;
  int M, N, K, lda, ldb, ldc;
  long sAz, sBz;
  int z0, zdiv, czmode;
  long sCz1, sCz2;
  const float* bias;
  long bstr;
  const float* resid;
  const int* flag;
};

template <int EPI, bool SKIPU, int BN>
__global__ __launch_bounds__(256) void gemm_bt(GemmP p) {
  int bx = blockIdx.x, by = blockIdx.y, bz = blockIdx.z;
  if (gridDim.z == 1) {  // XCD-aware swizzle (bijective when nwg%8==0)
    int n = gridDim.x * gridDim.y;
    if ((n & 7) == 0) {
      int wg = bx + gridDim.x * by;
      int s = (wg & 7) * (n >> 3) + (wg >> 3);
      by = s % gridDim.y; bx = s / gridDim.y;
    }
  }
  if (SKIPU && bx > by) return;  // causal: upper tiles never read
  constexpr int NJ = BN / 32;    // n-subtiles per wave
  __shared__ __align__(16) f16_t la[128 * 32];
  __shared__ __align__(16) f16_t lb[BN * 32];
  int tid = threadIdx.x;
  const f16_t* Ab = p.A + (long)bz * p.sAz;
  const f16_t* Bb = p.B + (long)bz * p.sBz;

  int r0 = tid >> 2;
  int c8 = (tid & 3) << 3;
  long ar0 = (long)by * 128 + r0;
  long ar1 = ar0 + 64;
  int brow0 = bx * BN + r0;      if (brow0 > p.N - 1) brow0 = p.N - 1;
  const f16_t* ag0 = Ab + ar0 * p.lda + c8;
  const f16_t* ag1 = Ab + ar1 * p.lda + c8;
  const f16_t* bg0 = Bb + (long)brow0 * p.ldb + c8;
  const f16_t* bg1 = nullptr;
  if constexpr (BN == 128) {
    int brow1 = bx * BN + 64 + r0; if (brow1 > p.N - 1) brow1 = p.N - 1;
    bg1 = Bb + (long)brow1 * p.ldb + c8;
  }
  f16_t* la0 = la + tid * 8; f16_t* la1 = la + 2048 + tid * 8;
  f16_t* lb0 = lb + tid * 8; f16_t* lb1 = lb + 2048 + tid * 8;

  int w = tid >> 6, l = tid & 63;
  int wm = (w >> 1) << 6, wn = (w & 1) * (BN / 2);
  int lr = l & 15, q = l >> 4;

  f4v acc[4][NJ];
  f4v zero = {0.f, 0.f, 0.f, 0.f};
#pragma unroll
  for (int i = 0; i < 4; ++i)
#pragma unroll
    for (int j = 0; j < NJ; ++j) acc[i][j] = zero;

  int nk = p.K >> 5;
  for (int kt = 0; kt < nk; ++kt) {
    __syncthreads();
    long ko = (long)kt << 5;
    gl2lds16(ag0 + ko, la0);
    gl2lds16(ag1 + ko, la1);
    gl2lds16(bg0 + ko, lb0);
    if constexpr (BN == 128) gl2lds16(bg1 + ko, lb1);
    __syncthreads();
    f16x8 af[4], bfr[NJ];
#pragma unroll
    for (int i = 0; i < 4; ++i) af[i] = *(const f16x8*)(la + (wm + i * 16 + lr) * 32 + q * 8);
#pragma unroll
    for (int j = 0; j < NJ; ++j) bfr[j] = *(const f16x8*)(lb + (wn + j * 16 + lr) * 32 + q * 8);
#pragma unroll
    for (int i = 0; i < 4; ++i)
#pragma unroll
      for (int j = 0; j < NJ; ++j)
        acc[i][j] = __builtin_amdgcn_mfma_f32_16x16x32_f16(af[i], bfr[j], acc[i][j], 0, 0, 0);
  }

  long cz;
  if (p.czmode == 1) { int z = p.z0 + bz; cz = (long)(z / p.zdiv) * p.sCz1 + (long)(z % p.zdiv) * p.sCz2; }
  else cz = (long)bz * p.sCz2;

#pragma unroll
  for (int i = 0; i < 4; ++i) {
    int gr0 = by * 128 + wm + i * 16 + q * 4;
#pragma unroll
    for (int j = 0; j < NJ; ++j) {
      int gc = bx * BN + wn + j * 16 + lr;
      if (gc >= p.N) continue;
      float bv = 0.f;
      if constexpr (EPI == 3 || EPI == 4) bv = p.bias[gc];
#pragma unroll
      for (int r = 0; r < 4; ++r) {
        int row = gr0 + r;
        if (row >= p.M) continue;
        float v = acc[i][j][r];
        if constexpr (EPI == 0) {
          ((float*)p.C)[cz + (long)row * p.ldc + gc] = v;
        } else if constexpr (EPI == 2) {
          ((f16_t*)p.C)[cz + (long)row * p.ldc + gc] = (f16_t)v;
        } else if constexpr (EPI == 3) {
          long ad = cz + (long)row * p.ldc + gc;
          ((float*)p.C)[ad] = v + bv + p.resid[ad];
        } else if constexpr (EPI == 4) {
          float t = v + bv; t = t > 0.f ? t : 0.f;
          ((f16_t*)p.C)[cz + (long)row * p.ldc + gc] = (f16_t)t;
        }
      }
    }
  }
}

// ---------------- 256x256 8-phase GEMM (T2+T3+T4+T5) ----------------
// C = A * B^T(storage); A (M x K) f16 row-major, B (N x K) f16 row-major.
// Requires: M%256==0, N%256==0, K%128==0, nwg%8==0. 512 threads = 8 waves (2M x 4N).
// LDS 128 KiB: A0|A1|B0|B1 K-tile buffers (256x64 f16 each), chunk-XOR swizzled.
// EPI: 1 QKV head-split f16 (+bias)   4 f16 +bias +relu   6 flag-dtype f32/bf16 out
struct Gemm8P {
  const f16_t* A; const f16_t* B; void* C;
  int M, N, K, lda, ldb, ldc;
  const float* bias;
  long bstr;
  const int* flag;
};

#define BARR()  asm volatile("s_barrier" ::: "memory")
#define WAITL0() do { asm volatile("s_waitcnt lgkmcnt(0)" ::: "memory"); __builtin_amdgcn_sched_barrier(0); } while (0)
#define WVM(n)  asm volatile("s_waitcnt vmcnt(" n ")" ::: "memory")

template <int EPI>
__global__ __launch_bounds__(512, 2) void gemm8p(Gemm8P p) {
  extern __shared__ __align__(16) f16_t lds[];
  constexpr int A0 = 0, A1 = 16384, B0 = 32768, B1 = 49152;  // f16 offsets
  int tid = threadIdx.x;

  // XCD-aware bijective swizzle (nwg % 8 == 0 guaranteed by host), by-fastest
  int nwg = gridDim.x * gridDim.y;
  int wg = blockIdx.x + gridDim.x * blockIdx.y;
  int s = (wg & 7) * (nwg >> 3) + (wg >> 3);
  int by = s % gridDim.y;
  int bx = s / gridDim.y;

  int wave = tid >> 6, l = tid & 63;
  int wr = wave >> 2, wc = wave & 3;     // 2 x 4 wave grid; per-wave out 128x64
  int lr = l & 15, q = l >> 4;

  // staging: lane covers row r8 (+64 on 2nd load) of a 128-row half, chunk ch of 8;
  // source chunk pre-swizzled so linear LDS + XOR read is conflict-free (rule 21)
  int r8 = tid >> 3, ch = tid & 7;
  int chs = ch ^ (r8 & 7);
  const f16_t* pA = p.A + ((long)by * 256 + r8) * p.lda + chs * 8;
  const f16_t* pB = p.B + ((long)bx * 256 + r8) * p.ldb + chs * 8;
  f16_t* ldsw = lds + tid * 8;  // = wave_base + lane*16B (linear, HW-required)

  auto SA = [&](int t, int h, int off) {
    const f16_t* g = pA + ((long)h * 128) * p.lda + (long)t * 64;
    gl2lds16(g, ldsw + off);
    gl2lds16(g + (long)64 * p.lda, ldsw + off + 4096);
  };
  auto SB = [&](int t, int h, int off) {
    const f16_t* g = pB + ((long)h * 128) * p.ldb + (long)t * 64;
    gl2lds16(g, ldsw + off);
    gl2lds16(g + (long)64 * p.ldb, ldsw + off + 4096);
  };

  f16x8 afr[4][2], bfr[2][2][2];
  auto LA = [&](int off, int qm) {
#pragma unroll
    for (int i = 0; i < 4; ++i) {
      int row = wr * 128 + qm * 64 + i * 16 + lr;
#pragma unroll
      for (int ks = 0; ks < 2; ++ks) {
        int c = ks * 4 + q;
        afr[i][ks] = *(const f16x8*)(lds + off + row * 64 + ((c ^ (lr & 7)) << 3));
      }
    }
  };
  auto LB = [&](int off, int qn) {
#pragma unroll
    for (int j = 0; j < 2; ++j) {
      int row = wc * 64 + qn * 32 + j * 16 + lr;
#pragma unroll
      for (int ks = 0; ks < 2; ++ks) {
        int c = ks * 4 + q;
        bfr[qn][j][ks] = *(const f16x8*)(lds + off + row * 64 + ((c ^ (lr & 7)) << 3));
      }
    }
  };

  f4v acc[8][4];
  f4v zero = {0.f, 0.f, 0.f, 0.f};
#pragma unroll
  for (int i = 0; i < 8; ++i)
#pragma unroll
    for (int j = 0; j < 4; ++j) acc[i][j] = zero;

  auto MM = [&](int qm, int qn) {
#pragma unroll
    for (int i = 0; i < 4; ++i)
#pragma unroll
      for (int j = 0; j < 2; ++j)
#pragma unroll
        for (int ks = 0; ks < 2; ++ks)
          acc[qm * 4 + i][qn * 2 + j] =
              __builtin_amdgcn_mfma_f32_16x16x32_f16(afr[i][ks], bfr[qn][j][ks],
                                                     acc[qm * 4 + i][qn * 2 + j], 0, 0, 0);
  };

  int npair = p.K >> 7;  // pairs of 64-wide K-tiles

  // prologue: tile0 fully, tile1 B-halves; vmcnt(4) -> tile0 landed, tile1-B in flight
  SB(0, 0, B0); SB(0, 1, B0 + 8192);
  SA(0, 0, A0); SA(0, 1, A0 + 8192);
  SB(1, 0, B1); SB(1, 1, B1 + 8192);
  WVM("4"); BARR();

  for (int kp = 0; kp < npair; ++kp) {
    int t1 = 2 * kp + 1, t2 = 2 * kp + 2, t3 = 2 * kp + 3;
    bool nl = (kp != npair - 1);
    // ph0: read buf0 A[qm0]+B[qn0]; stage t1 A-h0 -> buf1
    LA(A0, 0); LB(B0, 0);
    SA(t1, 0, A1);
    BARR(); WAITL0();
    __builtin_amdgcn_s_setprio(1); MM(0, 0); __builtin_amdgcn_s_setprio(0);
    BARR();
    // ph1: read B[qn1]; stage t1 A-h1
    LB(B0, 1);
    SA(t1, 1, A1 + 8192);
    BARR(); WAITL0();
    __builtin_amdgcn_s_setprio(1); MM(0, 1); __builtin_amdgcn_s_setprio(0);
    BARR();
    // ph2: read A[qm1]; stage t2 B-h0 -> buf0 (B region free after ph1)
    LA(A0, 1);
    if (nl) SB(t2, 0, B0);
    BARR(); WAITL0();
    __builtin_amdgcn_s_setprio(1); MM(1, 1); __builtin_amdgcn_s_setprio(0);
    BARR();
    // ph3: reuse regs; stage t2 B-h1; vmcnt ensures t1 fully staged before ph4
    if (nl) SB(t2, 1, B0 + 8192);
    BARR();
    __builtin_amdgcn_s_setprio(1); MM(1, 0); __builtin_amdgcn_s_setprio(0);
    if (nl) { WVM("4"); } else { WVM("0"); }
    BARR();
    // ph4: read buf1 A[qm0]+B[qn0]; stage t2 A-h0 -> buf0 (A region free after ph2)
    LA(A1, 0); LB(B1, 0);
    if (nl) SA(t2, 0, A0);
    BARR(); WAITL0();
    __builtin_amdgcn_s_setprio(1); MM(0, 0); __builtin_amdgcn_s_setprio(0);
    BARR();
    // ph5: read B[qn1]; stage t2 A-h1
    LB(B1, 1);
    if (nl) SA(t2, 1, A0 + 8192);
    BARR(); WAITL0();
    __builtin_amdgcn_s_setprio(1); MM(0, 1); __builtin_amdgcn_s_setprio(0);
    BARR();
    // ph6: read A[qm1]; stage t3 B-h0 -> buf1 (B region free after ph5)
    LA(A1, 1);
    if (nl) SB(t3, 0, B1);
    BARR(); WAITL0();
    __builtin_amdgcn_s_setprio(1); MM(1, 1); __builtin_amdgcn_s_setprio(0);
    BARR();
    // ph7: stage t3 B-h1; vmcnt ensures t2 staged before next ph0
    if (nl) SB(t3, 1, B1 + 8192);
    BARR();
    __builtin_amdgcn_s_setprio(1); MM(1, 0); __builtin_amdgcn_s_setprio(0);
    if (nl) WVM("4");
    BARR();
  }

  int flg = 0;
  if constexpr (EPI == 6) flg = *p.flag;

#pragma unroll
  for (int mi = 0; mi < 8; ++mi) {
    int grow = by * 256 + wr * 128 + mi * 16 + q * 4;
#pragma unroll
    for (int ni = 0; ni < 4; ++ni) {
      int gc = bx * 256 + wc * 64 + ni * 16 + lr;
      float bv = 0.f;
      if constexpr (EPI == 1) bv = p.bias[(long)(gc >> 10) * p.bstr + (gc & (DD - 1))];
      if constexpr (EPI == 4) bv = p.bias[gc];
#pragma unroll
      for (int r = 0; r < 4; ++r) {
        int row = grow + r;
        float v = acc[mi][ni][r];
        if constexpr (EPI == 1) {
          long ad = ((long)(gc >> 6) * p.M + row) * 64 + (gc & 63);
          ((f16_t*)p.C)[ad] = (f16_t)(v + bv);
        } else if constexpr (EPI == 4) {
          float t = v + bv; t = t > 0.f ? t : 0.f;
          ((f16_t*)p.C)[(long)row * p.ldc + gc] = (f16_t)t;
        } else if constexpr (EPI == 6) {
          long ad = (long)row * p.ldc + gc;
          if (flg) ((bf16_t*)p.C)[ad] = __float2bfloat16(v);
          else     ((float*)p.C)[ad] = v;
        }
      }
    }
  }
}

// ---------------- host ----------------
extern "C" void kernel_launch(void* const* d_in, const int* in_sizes, int n_in,
                              void* d_out, int out_size, void* d_ws, size_t ws_size,
                              hipStream_t stream) {
  (void)in_sizes; (void)n_in; (void)out_size;
  const int*  tok = (const int*)d_in[0];
  const void* E_  = d_in[1];  const void* P_  = d_in[2];
  const void* Wq_ = d_in[3];  const void* bq_ = d_in[4];
  const void* Wk_ = d_in[5];  const void* bk_ = d_in[6];
  const void* Wv_ = d_in[7];  const void* bv_ = d_in[8];
  const void* W0_ = d_in[9];  const void* b0_ = d_in[10];
  const void* g1_ = d_in[11]; const void* be1_ = d_in[12];
  const void* g2_ = d_in[13]; const void* be2_ = d_in[14];
  const void* W1_ = d_in[15]; const void* b1_ = d_in[16];
  const void* W2_ = d_in[17]; const void* b2_ = d_in[18];

  // allow 128 KiB dynamic LDS on the 8-phase kernels (idempotent, capture-safe)
  (void)hipFuncSetAttribute(reinterpret_cast<const void*>(&gemm8p<1>),
                            hipFuncAttributeMaxDynamicSharedMemorySize, 131072);
  (void)hipFuncSetAttribute(reinterpret_cast<const void*>(&gemm8p<4>),
                            hipFuncAttributeMaxDynamicSharedMemorySize, 131072);
  (void)hipFuncSetAttribute(reinterpret_cast<const void*>(&gemm8p<6>),
                            hipFuncAttributeMaxDynamicSharedMemorySize, 131072);

  char* wsb = (char*)d_ws;
  size_t off = 0;
  auto alloc = [&](size_t bytes) -> void* {
    off = (off + 255) & ~(size_t)255;
    void* p = wsb + off;
    off += bytes;
    return p;
  };

  int*    flag  = (int*)alloc(4);
  f16_t*  Ef    = (f16_t*)alloc((size_t)VV * DD * 2);
  f16_t*  Pf    = (f16_t*)alloc((size_t)SS * DD * 2);
  f16_t*  Wqkvt = (f16_t*)alloc((size_t)LL * 3 * DD * DD * 2); // [l][t*1024+h*64+e][d]
  f16_t*  W0t   = (f16_t*)alloc((size_t)LL * DD * DD * 2);     // [l][n][d]
  f16_t*  W1t   = (f16_t*)alloc((size_t)LL * DFFN * DD * 2);
  f16_t*  W2t   = (f16_t*)alloc((size_t)LL * DD * DFFN * 2);
  float*  bqkvf = (float*)alloc((size_t)3 * LL * HH * DHH * 4); // [t][l][h][e]
  float*  b0f   = (float*)alloc((size_t)LL * DD * 4);
  float*  b1f   = (float*)alloc((size_t)LL * DFFN * 4);
  float*  b2f   = (float*)alloc((size_t)LL * DD * 4);
  float*  g1f   = (float*)alloc((size_t)LL * DD * 4);
  float*  be1f  = (float*)alloc((size_t)LL * DD * 4);
  float*  g2f   = (float*)alloc((size_t)LL * DD * 4);
  float*  be2f  = (float*)alloc((size_t)LL * DD * 4);
  float*  X     = (float*)alloc((size_t)BSZ * DD * 4);          // fp32 residual stream
  f16_t*  hbuf  = (f16_t*)alloc((size_t)BSZ * DD * 2);
  f16_t*  QKVb  = (f16_t*)alloc((size_t)3 * HH * BB * SS * DHH * 2); // [t*16+h][b*S+s][e]
  f16_t*  Vt    = (f16_t*)alloc((size_t)HH * BB * DHH * SS * 2);     // [h][b][e][s]
  f16_t*  attn  = (f16_t*)alloc((size_t)BSZ * DD * 2);               // [b][s][h*64+e]
  f16_t*  ff    = (f16_t*)alloc((size_t)BSZ * DFFN * 2);

  f16_t* Qb = QKVb;
  f16_t* Kb = QKVb + (size_t)HH * BB * SS * DHH;
  f16_t* Vb = QKVb + (size_t)2 * HH * BB * SS * DHH;

  size_t rem = ws_size > off ? ws_size - off : 0;
  int CH = 64;
  while (CH > 1 && ((size_t)CH * SS * SS * 2 + 1024) > rem) CH >>= 1;
  f16_t* scoresB = (f16_t*)alloc((size_t)CH * SS * SS * 2);

  dim3 blk(256);

  // --- dtype detect + ingest ---
  detect_k<<<dim3(1), blk, 0, stream>>>((const unsigned int*)E_, flag);
  conv_f16_k<<<dim3(8192), blk, 0, stream>>>(E_, Ef, (long)VV * DD, flag, -1);
  conv_f16_k<<<dim3(1024), blk, 0, stream>>>(P_, Pf, (long)SS * DD, flag, -1);
  conv_f32_k<<<dim3(16), blk, 0, stream>>>(bq_, bqkvf, (long)LL * HH * DHH, flag);
  conv_f32_k<<<dim3(16), blk, 0, stream>>>(bk_, bqkvf + (size_t)LL * HH * DHH, (long)LL * HH * DHH, flag);
  conv_f32_k<<<dim3(16), blk, 0, stream>>>(bv_, bqkvf + (size_t)2 * LL * HH * DHH, (long)LL * HH * DHH, flag);
  conv_f32_k<<<dim3(16), blk, 0, stream>>>(b0_, b0f, (long)LL * DD, flag);
  conv_f32_k<<<dim3(64), blk, 0, stream>>>(b1_, b1f, (long)LL * DFFN, flag);
  conv_f32_k<<<dim3(16), blk, 0, stream>>>(b2_, b2f, (long)LL * DD, flag);
  conv_f32_k<<<dim3(16), blk, 0, stream>>>(g1_, g1f, (long)LL * DD, flag);
  conv_f32_k<<<dim3(16), blk, 0, stream>>>(be1_, be1f, (long)LL * DD, flag);
  conv_f32_k<<<dim3(16), blk, 0, stream>>>(g2_, g2f, (long)LL * DD, flag);
  conv_f32_k<<<dim3(16), blk, 0, stream>>>(be2_, be2f, (long)LL * DD, flag);

  const long W3 = (long)3 * DD * DD;
  transpose_k<<<dim3(2, 32, LL * HH), dim3(32, 8), 0, stream>>>(Wq_, Wqkvt + 0 * DD * DD, DD, DHH, flag, -1,
                                                                W3, HH, (long)DHH * DD);
  transpose_k<<<dim3(2, 32, LL * HH), dim3(32, 8), 0, stream>>>(Wk_, Wqkvt + 1 * DD * DD, DD, DHH, flag, -1,
                                                                W3, HH, (long)DHH * DD);
  transpose_k<<<dim3(2, 32, LL * HH), dim3(32, 8), 0, stream>>>(Wv_, Wqkvt + 2 * DD * DD, DD, DHH, flag, -1,
                                                                W3, HH, (long)DHH * DD);
  transpose_k<<<dim3(32, 32, LL), dim3(32, 8), 0, stream>>>(W0_, W0t, DD, DD, flag, -1,
                                                            (long)DD * DD, 1, 0);
  transpose_k<<<dim3(128, 32, LL), dim3(32, 8), 0, stream>>>(W1_, W1t, DD, DFFN, flag, -1,
                                                             (long)DD * DFFN, 1, 0);
  transpose_k<<<dim3(32, 128, LL), dim3(32, 8), 0, stream>>>(W2_, W2t, DFFN, DD, flag, -1,
                                                             (long)DFFN * DD, 1, 0);

  // --- embedding ---
  embed_k<<<dim3(BSZ), blk, 0, stream>>>(tok, Ef, Pf, X);

  // --- layers ---
  for (int l = 0; l < LL; ++l) {
    ln_k<<<dim3(BSZ), blk, 0, stream>>>(X, g1f + (long)l * DD, be1f + (long)l * DD, hbuf);

    // fused QKV projection: 8-phase 256^2 kernel, head-split epilogue
    Gemm8P q8{};
    q8.A = hbuf; q8.B = Wqkvt + (long)l * W3; q8.C = QKVb;
    q8.M = BSZ; q8.N = 3 * DD; q8.K = DD; q8.lda = DD; q8.ldb = DD; q8.ldc = 0;
    q8.bias = bqkvf + (long)l * HH * DHH; q8.bstr = (long)LL * HH * DHH; q8.flag = nullptr;
    gemm8p<1><<<dim3(12, 16), dim3(512), 131072, stream>>>(q8);

    // V -> Vt [h][b][e][s]
    transpose_k<<<dim3(2, 32, HH * BB), dim3(32, 8), 0, stream>>>((const void*)Vb, Vt, SS, DHH, nullptr, 2,
                                                                  (long)DHH * SS, 1, 0);

    int nch = (HH * BB) / CH;
    for (int c = 0; c < nch; ++c) {
      int z0 = c * CH;
      // scores = Q K^T (lower-triangular tiles only), f16
      GemmP ps{};
      ps.A = Qb + (long)z0 * SS * DHH; ps.sAz = (long)SS * DHH; ps.lda = DHH;
      ps.B = Kb + (long)z0 * SS * DHH; ps.sBz = (long)SS * DHH; ps.ldb = DHH;
      ps.M = SS; ps.N = SS; ps.K = DHH;
      ps.C = scoresB; ps.ldc = SS; ps.czmode = 0; ps.z0 = 0; ps.zdiv = 1;
      ps.sCz1 = 0; ps.sCz2 = (long)SS * SS;
      ps.bias = nullptr; ps.bstr = 0; ps.resid = nullptr; ps.flag = nullptr;
      gemm_bt<2, true, 128><<<dim3(8, 8, CH), blk, 0, stream>>>(ps);

      softmax_k<<<dim3(SS, CH), blk, 0, stream>>>(scoresB, scoresB, tok, z0);

      // attn = P V  -> attn[b][s][h*64+e]
      GemmP pp{};
      pp.A = scoresB; pp.sAz = (long)SS * SS; pp.lda = SS;
      pp.B = Vt + (long)z0 * DHH * SS; pp.sBz = (long)DHH * SS; pp.ldb = SS;
      pp.M = SS; pp.N = DHH; pp.K = SS;
      pp.C = attn; pp.ldc = DD; pp.czmode = 1; pp.z0 = z0; pp.zdiv = BB;
      pp.sCz1 = DHH; pp.sCz2 = (long)SS * DD;
      pp.bias = nullptr; pp.bstr = 0; pp.resid = nullptr; pp.flag = nullptr;
      gemm_bt<2, false, 64><<<dim3(1, 8, CH), blk, 0, stream>>>(pp);
    }

    // X = attn @ W0^T + b0 + X
    GemmP p0{};
    p0.A = attn; p0.lda = DD; p0.M = BSZ; p0.N = DD; p0.K = DD;
    p0.B = W0t + (long)l * DD * DD; p0.ldb = DD;
    p0.C = X; p0.ldc = DD; p0.czmode = 0; p0.z0 = 0; p0.zdiv = 1;
    p0.sAz = 0; p0.sBz = 0; p0.sCz1 = 0; p0.sCz2 = 0;
    p0.bias = b0f + (long)l * DD; p0.bstr = 0; p0.resid = X; p0.flag = nullptr;
    gemm_bt<3, false, 128><<<dim3(8, 32, 1), blk, 0, stream>>>(p0);

    ln_k<<<dim3(BSZ), blk, 0, stream>>>(X, g2f + (long)l * DD, be2f + (long)l * DD, hbuf);

    // ff = relu(h @ W1^T + b1): 8-phase kernel
    Gemm8P f8{};
    f8.A = hbuf; f8.B = W1t + (long)l * DFFN * DD; f8.C = ff;
    f8.M = BSZ; f8.N = DFFN; f8.K = DD; f8.lda = DD; f8.ldb = DD; f8.ldc = DFFN;
    f8.bias = b1f + (long)l * DFFN; f8.bstr = 0; f8.flag = nullptr;
    gemm8p<4><<<dim3(16, 16), dim3(512), 131072, stream>>>(f8);

    // X = ff @ W2^T + b2 + X
    GemmP p2{};
    p2.A = ff; p2.lda = DFFN; p2.M = BSZ; p2.N = DD; p2.K = DFFN;
    p2.B = W2t + (long)l * DD * DFFN; p2.ldb = DFFN;
    p2.C = X; p2.ldc = DD; p2.czmode = 0; p2.z0 = 0; p2.zdiv = 1;
    p2.sAz = 0; p2.sBz = 0; p2.sCz1 = 0; p2.sCz2 = 0;
    p2.bias = b2f + (long)l * DD; p2.bstr = 0; p2.resid = X; p2.flag = nullptr;
    gemm_bt<3, false, 128><<<dim3(8, 32, 1), blk, 0, stream>>>(p2);
  }

  // logits = X @ E^T : 8-phase kernel (N=32000 = 125*256 exact)
  conv_f16_k<<<dim3(4096), blk, 0, stream>>>((const void*)X, hbuf, (long)BSZ * DD, flag, 0);
  Gemm8P pl{};
  pl.A = hbuf; pl.B = Ef; pl.C = d_out;
  pl.M = BSZ; pl.N = VV; pl.K = DD; pl.lda = DD; pl.ldb = DD; pl.ldc = VV;
  pl.bias = nullptr; pl.bstr = 0; pl.flag = flag;
  gemm8p<6><<<dim3(125, 16), dim3(512), 131072, stream>>>(pl);
}